// Round 1
// baseline (68.894 us; speedup 1.0000x reference)
//
#include <hip/hip_runtime.h>
#include <stdint.h>

// ---------------------------------------------------------------------------
// QFF radiance field forward, fully fused, bf16 MFMA (gfx950 32x32x16).
// Swapped operands: D = W^T (A) @ X^T (B)  ->  D[out][point], col = point.
// Activations never touch LDS: D -> next B via cvt_pk_bf16 + permlane32_swap.
// ---------------------------------------------------------------------------

typedef __attribute__((ext_vector_type(8)))  short short8;   // 8 x bf16 (4 VGPRs)
typedef __attribute__((ext_vector_type(16))) float f32x16;   // MFMA 32x32 C/D

#define GRID_FLOATS (24 * 80 * 4)

__device__ __forceinline__ uint32_t cvt_pk_bf16(float lo, float hi) {
  uint32_t r;
  asm("v_cvt_pk_bf16_f32 %0, %1, %2" : "=v"(r) : "v"(lo), "v"(hi));
  return r;
}
// v_permlane32_swap_b32: a.hi32lanes <-> b.lo32lanes
// after: a = [a_lo | b_lo], b = [a_hi | b_hi]
__device__ __forceinline__ void plswap_u(uint32_t &a, uint32_t &b) {
  asm("v_permlane32_swap_b32 %0, %1" : "+v"(a), "+v"(b));
}
__device__ __forceinline__ void plswap_f(float &a, float &b) {
  asm("v_permlane32_swap_b32 %0, %1" : "+v"(a), "+v"(b));
}

union FragU { uint32_t u[4]; short8 s; };
__device__ __forceinline__ short8 mk_frag(uint32_t a, uint32_t b, uint32_t c, uint32_t d) {
  FragU f; f.u[0] = a; f.u[1] = b; f.u[2] = c; f.u[3] = d; return f.s;
}

#define MFMA(A, B, C) __builtin_amdgcn_mfma_f32_32x32x16_bf16((A), (B), (C), 0, 0, 0)

// A-fragment of W^T for swapped-operand mfma: A[out][k] = W[k][out].
// Lane layout (32x32x16 bf16): row(out) = lane&31, k = (lane>>5)*8 + i.
__device__ __forceinline__ short8 load_wfragT(const float* __restrict__ W, int K, int C,
                                              int k0, int outbase, int lane) {
  const int g = (lane >> 5) & 1, o = lane & 31;
  const int out = outbase + o;
  uint32_t w[4];
#pragma unroll
  for (int p2 = 0; p2 < 4; ++p2) {
    int k = k0 + g * 8 + 2 * p2;
    float lo = (out < C && k     < K) ? W[k * C + out]       : 0.0f;
    float hi = (out < C && k + 1 < K) ? W[(k + 1) * C + out] : 0.0f;
    w[p2] = cvt_pk_bf16(lo, hi);
  }
  return mk_frag(w[0], w[1], w[2], w[3]);
}

// D (32 outs, regs BASE..BASE+7 cover rows base..base+15) -> B-frag of next layer.
// D row map: out = (reg&3) + 8*(reg>>2) + 4*g.  B needs k = 8g+i per lane.
template<int BASE, bool RELU>
__device__ __forceinline__ short8 packB(const f32x16& a) {
  float r0 = a[BASE + 0], r1 = a[BASE + 1], r2 = a[BASE + 2], r3 = a[BASE + 3];
  float r4 = a[BASE + 4], r5 = a[BASE + 5], r6 = a[BASE + 6], r7 = a[BASE + 7];
  if (RELU) {
    r0 = fmaxf(r0, 0.f); r1 = fmaxf(r1, 0.f); r2 = fmaxf(r2, 0.f); r3 = fmaxf(r3, 0.f);
    r4 = fmaxf(r4, 0.f); r5 = fmaxf(r5, 0.f); r6 = fmaxf(r6, 0.f); r7 = fmaxf(r7, 0.f);
  }
  uint32_t x = cvt_pk_bf16(r0, r1), y = cvt_pk_bf16(r4, r5);
  plswap_u(x, y);   // x = word0 (k 8g+0,1), y = word2 (k 8g+4,5)
  uint32_t z = cvt_pk_bf16(r2, r3), w = cvt_pk_bf16(r6, r7);
  plswap_u(z, w);   // z = word1, w = word3
  return mk_frag(x, z, y, w);
}

// line = sc*3 + dim, sc<4 -> sin(p*f), sc>=4 -> cos(p*f). Compile-time LINE.
template<int LINE>
__device__ __forceinline__ float coord_line(float px, float py, float pz) {
  constexpr int sc = LINE / 3, dim = LINE % 3;
  constexpr float FRQ[4] = {2.0f, 6.3496042f, 20.158737f, 64.0f};
  constexpr float m = FRQ[sc & 3] * 0.15915494309189535f;  // to revolutions
  float pv = (dim == 0) ? px : ((dim == 1) ? py : pz);
  float r = pv * m;
  r = r - floorf(r);
  return (sc < 4) ? __builtin_amdgcn_sinf(r) : __builtin_amdgcn_cosf(r);
}

// One K=16 step of the encoding B-matrix (lines 4T..4T+3); this lane supplies
// lines 4T+2g, 4T+2g+1 (k = 16T + 8g + line_in*4 + feat) for point (lane&31).
template<int T>
__device__ __forceinline__ short8 enc_frag(float px, float py, float pz, int g,
                                           const float4* __restrict__ gs4) {
  float cA = coord_line<4 * T + 0>(px, py, pz);
  float cB = coord_line<4 * T + 1>(px, py, pz);
  float cC = coord_line<4 * T + 2>(px, py, pz);
  float cD = coord_line<4 * T + 3>(px, py, pz);
  float c0 = g ? cC : cA;
  float c1 = g ? cD : cB;
  float u0 = (c0 + 1.0f) * 39.5f;
  float u1 = (c1 + 1.0f) * 39.5f;
  int i0 = (int)floorf(u0); i0 = i0 < 0 ? 0 : (i0 > 78 ? 78 : i0);
  int i1 = (int)floorf(u1); i1 = i1 < 0 ? 0 : (i1 > 78 ? 78 : i1);
  float w0 = u0 - (float)i0;
  float w1 = u1 - (float)i1;
  int line0 = 4 * T + 2 * g;
  float4 a0 = gs4[line0 * 80 + i0];
  float4 a1 = gs4[line0 * 80 + i0 + 1];
  float4 b0 = gs4[(line0 + 1) * 80 + i1];
  float4 b1 = gs4[(line0 + 1) * 80 + i1 + 1];
  float f0 = fmaf(w0, a1.x - a0.x, a0.x);
  float f1 = fmaf(w0, a1.y - a0.y, a0.y);
  float f2 = fmaf(w0, a1.z - a0.z, a0.z);
  float f3 = fmaf(w0, a1.w - a0.w, a0.w);
  float f4 = fmaf(w1, b1.x - b0.x, b0.x);
  float f5 = fmaf(w1, b1.y - b0.y, b0.y);
  float f6 = fmaf(w1, b1.z - b0.z, b0.z);
  float f7 = fmaf(w1, b1.w - b0.w, b0.w);
  return mk_frag(cvt_pk_bf16(f0, f1), cvt_pk_bf16(f2, f3),
                 cvt_pk_bf16(f4, f5), cvt_pk_bf16(f6, f7));
}

__global__ __launch_bounds__(256, 2)
void qff_fwd(const float* __restrict__ pos, const float* __restrict__ dir,
             const float* __restrict__ grid,
             const float* __restrict__ w1, const float* __restrict__ w2,
             const float* __restrict__ wc1, const float* __restrict__ wc2,
             const float* __restrict__ wc3,
             float* __restrict__ out, int Npts) {
  __shared__ __align__(16) float gs[GRID_FLOATS];
  for (int i = threadIdx.x; i < GRID_FLOATS; i += 256) gs[i] = grid[i];

  const int lane = threadIdx.x & 63;
  const int wid  = threadIdx.x >> 6;
  const int g    = lane >> 5;
  const int o    = lane & 31;

  // One-time weight A-fragments (bf16) into registers: 32 frags = 128 VGPRs.
  short8 w1f0[6], w1f1[6], w2f[4], wc1f0[2], wc1f1[2], wc2f0[4], wc2f1[4], wc3f[4];
#pragma unroll
  for (int t = 0; t < 6; ++t) {
    w1f0[t] = load_wfragT(w1, 96, 64, 16 * t, 0,  lane);
    w1f1[t] = load_wfragT(w1, 96, 64, 16 * t, 32, lane);
  }
#pragma unroll
  for (int t = 0; t < 4; ++t) {
    w2f[t]   = load_wfragT(w2,  64, 16, 16 * t, 0,  lane);   // outs 16..31 zero-padded
    wc2f0[t] = load_wfragT(wc2, 64, 64, 16 * t, 0,  lane);
    wc2f1[t] = load_wfragT(wc2, 64, 64, 16 * t, 32, lane);
    wc3f[t]  = load_wfragT(wc3, 64, 3,  16 * t, 0,  lane);   // outs 3..31 zero-padded
  }
#pragma unroll
  for (int t = 0; t < 2; ++t) {
    wc1f0[t] = load_wfragT(wc1, 31, 64, 16 * t, 0,  lane);   // k=31 zero-padded
    wc1f1[t] = load_wfragT(wc1, 31, 64, 16 * t, 32, lane);
  }

  __syncthreads();
  const float4* gs4 = reinterpret_cast<const float4*>(gs);

  const f32x16 Z = {0,0,0,0, 0,0,0,0, 0,0,0,0, 0,0,0,0};
  const int ntile = Npts >> 7;  // 128 points per block-tile (N is a multiple of 128)

  for (int tb = blockIdx.x; tb < ntile; tb += gridDim.x) {
    const int p = (tb << 7) + (wid << 5) + o;   // this lane's point (both halves)
    float px = pos[3 * p + 0], py = pos[3 * p + 1], pz = pos[3 * p + 2];

    // ---- L1: enc(96) @ w_geom1 -> h1(64) ----
    f32x16 acc0 = Z, acc1 = Z;
#define L1STEP(T) { short8 bf = enc_frag<T>(px, py, pz, g, gs4); \
                    acc0 = MFMA(w1f0[T], bf, acc0); \
                    acc1 = MFMA(w1f1[T], bf, acc1); }
    L1STEP(0) L1STEP(1) L1STEP(2) L1STEP(3) L1STEP(4) L1STEP(5)
#undef L1STEP

    short8 hb0 = packB<0, true>(acc0), hb1 = packB<8, true>(acc0);
    short8 hb2 = packB<0, true>(acc1), hb3 = packB<8, true>(acc1);

    // ---- L2: h1 @ w_geom2 -> f(16)  (no relu) ----
    f32x16 acc2 = Z;
    acc2 = MFMA(w2f[0], hb0, acc2);
    acc2 = MFMA(w2f[1], hb1, acc2);
    acc2 = MFMA(w2f[2], hb2, acc2);
    acc2 = MFMA(w2f[3], hb3, acc2);
    float sigma = __expf(acc2[0] - 1.0f);  // valid on g==0 lanes (out0 = raw_sigma)

    // ---- spherical harmonics (hc k 0..15); lane half g supplies sh[8g..8g+7] ----
    float dx = dir[3 * p + 0], dy = dir[3 * p + 1], dz = dir[3 * p + 2];
    float xx = dx * dx, yy = dy * dy, zz = dz * dz;
    float xy = dx * dy, yz = dy * dz, xz = dx * dz;
    float s0, s1, s2, s3, s4, s5, s6, s7;
    if (g == 0) {
      s0 = 0.28209479177387814f;
      s1 = -0.48860251190291987f * dy;
      s2 =  0.48860251190291987f * dz;
      s3 = -0.48860251190291987f * dx;
      s4 =  1.0925484305920792f * xy;
      s5 = -1.0925484305920792f * yz;
      s6 =  0.94617469575756f * zz - 0.31539156525252f;
      s7 = -1.0925484305920792f * xz;
    } else {
      s0 =  0.5462742152960396f * (xx - yy);
      s1 = -0.5900435899266435f * dy * (3.0f * xx - yy);
      s2 =  2.890611442640554f * xy * dz;
      s3 = -0.4570457994644657f * dy * (4.0f * zz - xx - yy);
      s4 =  0.37317633259011546f * dz * (2.0f * zz - 3.0f * xx - 3.0f * yy);
      s5 = -0.4570457994644657f * dx * (4.0f * zz - xx - yy);
      s6 =  1.445305721320277f * dz * (xx - yy);
      s7 = -0.5900435899266435f * dx * (xx - 3.0f * yy);
    }
    short8 shB = mk_frag(cvt_pk_bf16(s0, s1), cvt_pk_bf16(s2, s3),
                         cvt_pk_bf16(s4, s5), cvt_pk_bf16(s6, s7));

    // ---- feature = f[1..15] -> hc k 16..30 (k31 hits zero-padded wc1 row) ----
    uint32_t e0 = cvt_pk_bf16(acc2[1], acc2[2]);   // g0:(out1,2)  g1:(out5,6)
    uint32_t e2 = cvt_pk_bf16(acc2[5], acc2[6]);   // g0:(out9,10) g1:(out13,14)
    plswap_u(e0, e2);                              // e0 -> word0, e2 -> word2
    float a3 = acc2[3], b7 = acc2[7];
    plswap_f(a3, b7);                              // a3: g0 out3 / g1 out11 ; b7: g0 out7 / g1 out15
    float cc0 = acc2[0], d4 = acc2[4];
    plswap_f(cc0, d4);                             // d4: g0 out4 / g1 out12
    uint32_t e1 = cvt_pk_bf16(a3, d4);
    uint32_t e3 = cvt_pk_bf16(b7, acc2[4]);        // second: g0 out8 / g1 pad(k31, zero weight)
    short8 featB = mk_frag(e0, e1, e2, e3);

    // ---- L3: hc(32) @ w_color1 -> h2(64), relu ----
    f32x16 acc3a = Z, acc3b = Z;
    acc3a = MFMA(wc1f0[0], shB,   acc3a);
    acc3a = MFMA(wc1f0[1], featB, acc3a);
    acc3b = MFMA(wc1f1[0], shB,   acc3b);
    acc3b = MFMA(wc1f1[1], featB, acc3b);

    short8 g2b0 = packB<0, true>(acc3a), g2b1 = packB<8, true>(acc3a);
    short8 g2b2 = packB<0, true>(acc3b), g2b3 = packB<8, true>(acc3b);

    // ---- L4: h2 @ w_color2 -> h3(64), relu ----
    f32x16 acc4a = Z, acc4b = Z;
    acc4a = MFMA(wc2f0[0], g2b0, acc4a);
    acc4a = MFMA(wc2f0[1], g2b1, acc4a);
    acc4a = MFMA(wc2f0[2], g2b2, acc4a);
    acc4a = MFMA(wc2f0[3], g2b3, acc4a);
    acc4b = MFMA(wc2f1[0], g2b0, acc4b);
    acc4b = MFMA(wc2f1[1], g2b1, acc4b);
    acc4b = MFMA(wc2f1[2], g2b2, acc4b);
    acc4b = MFMA(wc2f1[3], g2b3, acc4b);

    short8 g3b0 = packB<0, true>(acc4a), g3b1 = packB<8, true>(acc4a);
    short8 g3b2 = packB<0, true>(acc4b), g3b3 = packB<8, true>(acc4b);

    // ---- L5: h3 @ w_color3 -> rgb(3), sigmoid ----
    f32x16 acc5 = Z;
    acc5 = MFMA(wc3f[0], g3b0, acc5);
    acc5 = MFMA(wc3f[1], g3b1, acc5);
    acc5 = MFMA(wc3f[2], g3b2, acc5);
    acc5 = MFMA(wc3f[3], g3b3, acc5);

    if (lane < 32) {   // g==0 lanes hold outs 0..3 in regs 0..3
      float rr = 1.0f / (1.0f + __expf(-acc5[0]));
      float gg = 1.0f / (1.0f + __expf(-acc5[1]));
      float bb = 1.0f / (1.0f + __expf(-acc5[2]));
      out[3 * p + 0] = rr;
      out[3 * p + 1] = gg;
      out[3 * p + 2] = bb;
      out[3 * Npts + p] = sigma;
    }
  }
}

extern "C" void kernel_launch(void* const* d_in, const int* in_sizes, int n_in,
                              void* d_out, int out_size, void* d_ws, size_t ws_size,
                              hipStream_t stream) {
  const float* pos  = (const float*)d_in[0];
  const float* dirs = (const float*)d_in[1];
  const float* grid = (const float*)d_in[2];
  const float* w1   = (const float*)d_in[3];
  const float* w2   = (const float*)d_in[4];
  const float* wc1  = (const float*)d_in[5];
  const float* wc2  = (const float*)d_in[6];
  const float* wc3  = (const float*)d_in[7];
  float* out = (float*)d_out;
  const int Npts = in_sizes[0] / 3;

  qff_fwd<<<dim3(512), dim3(256), 0, stream>>>(pos, dirs, grid, w1, w2, wc1, wc2, wc3,
                                               out, Npts);
}

// Round 3
// 53.136 us; speedup vs baseline: 1.2965x; 1.2965x over previous
//
#include <hip/hip_runtime.h>
#include <stdint.h>

// ---------------------------------------------------------------------------
// QFF radiance field forward, fully fused, f16 MFMA (gfx950 32x32x16).
// Swapped operands: D = W^T (A) @ X^T (B)  ->  D[out][point], col = point.
// Weights live in LDS in fragment-shaped f16 layout (one ds_read_b128 per
// A-fragment, immediate offsets). Activations never touch LDS: D -> next B
// via v_cvt_pkrtz + v_permlane32_swap_b32.
// ---------------------------------------------------------------------------

typedef _Float16 half8  __attribute__((ext_vector_type(8)));
typedef _Float16 h2     __attribute__((ext_vector_type(2)));
typedef float    f32x16 __attribute__((ext_vector_type(16)));

union FragU { uint32_t u[4]; uint4 q; half8 h; };
union H2U   { uint32_t u; h2 h; };

static __device__ __forceinline__ h2 bch2(uint32_t v) { H2U x; x.u = v; return x.h; }
static __device__ __forceinline__ uint32_t bcu(h2 v)  { H2U x; x.h = v; return x.u; }

// cvt_pkrtz returns a __fp16 vector; bit-cast to our _Float16 vector type.
static __device__ __forceinline__ h2 cvtpk(float lo, float hi) {
  return __builtin_bit_cast(h2, __builtin_amdgcn_cvt_pkrtz(lo, hi));
}
static __device__ __forceinline__ uint32_t pkrtz(float lo, float hi) {
  return bcu(cvtpk(lo, hi));
}
// v_permlane32_swap_b32: after: a = [a_lo | b_lo], b = [a_hi | b_hi] (lane halves)
static __device__ __forceinline__ void plswap_u(uint32_t &a, uint32_t &b) {
  asm("v_permlane32_swap_b32 %0, %1" : "+v"(a), "+v"(b));
}
static __device__ __forceinline__ void plswap_f(float &a, float &b) {
  asm("v_permlane32_swap_b32 %0, %1" : "+v"(a), "+v"(b));
}
static __device__ __forceinline__ half8 mk_frag(uint32_t a, uint32_t b, uint32_t c, uint32_t d) {
  FragU f; f.u[0] = a; f.u[1] = b; f.u[2] = c; f.u[3] = d; return f.h;
}
static __device__ __forceinline__ uint32_t maxz(uint32_t v) {  // packed relu
  h2 h = bch2(v); h = __builtin_elementwise_max(h, (h2)(_Float16)0.0f); return bcu(h);
}
static __device__ __forceinline__ unsigned short f16b(float v) {
  _Float16 h = (_Float16)v; return __builtin_bit_cast(unsigned short, h);
}

#define MFMA(A, B, C) __builtin_amdgcn_mfma_f32_32x32x16_f16((A), (B), (C), 0, 0, 0)

// ---- LDS layout (bytes) ----
// W^T f16, row = out, padded k-stride; all strides are odd multiples of 16B.
#define W1OFF   0      // 64 rows x 208 B (kpad=104)  = 13312
#define W2OFF   13312  // 32 rows x 144 B (kpad=72)   = 4608   (outs 16..31 zero)
#define WC1OFF  17920  // 64 rows x  80 B (kpad=40)   = 5120   (k=31 zero)
#define WC2OFF  23040  // 64 rows x 144 B             = 9216
#define WC3OFF  32256  // 32 rows x 144 B             = 4608   (outs 3..31 zero)
#define GROFF   36864  // grid f16 [24][80][4] halves = 15360
#define LDSZ    52224
#define WBYTES  36864

static __device__ __forceinline__ half8 ldw(const unsigned char* s, int row, int off) {
  FragU f; f.q = *(const uint4*)(s + row + off); return f.h;
}

// D (rows BASE..BASE+7 of acc cover 16 outs) -> B-frag of next layer.
template<int BASE, bool RELU>
static __device__ __forceinline__ half8 packB(const f32x16& a) {
  uint32_t x = pkrtz(a[BASE + 0], a[BASE + 1]);
  uint32_t z = pkrtz(a[BASE + 2], a[BASE + 3]);
  uint32_t y = pkrtz(a[BASE + 4], a[BASE + 5]);
  uint32_t w = pkrtz(a[BASE + 6], a[BASE + 7]);
  if (RELU) { x = maxz(x); z = maxz(z); y = maxz(y); w = maxz(w); }
  plswap_u(x, y);
  plswap_u(z, w);
  return mk_frag(x, z, y, w);
}

struct Pre {
  float m[6];   // freq/(2pi) per coord slot (period-6)
  int   gb[6];  // grid base in 8B units: 4608 + line*80
  int   a13, a9, a5;  // per-lane weight row offsets (+16*g folded in)
};

// Coord J (0..11): line = 4*(J/2) + 2g + (J&1); J>=6 -> +12 lines (cos block).
template<int J>
static __device__ __forceinline__ void gather(const Pre& pre, float q0, float q1, float q2,
                                              const unsigned char* lds,
                                              uint32_t& w01, uint32_t& w23) {
  constexpr int jm = J % 6;
  constexpr int DIMP[6] = {0, 1, 1, 2, 2, 0};
  float q = (DIMP[jm] == 0) ? q0 : ((DIMP[jm] == 1) ? q1 : q2);
  float r = fmaf(q, pre.m[jm], (J < 6) ? 0.0f : 0.25f);   // cos = sin(x + 1/4 rev)
  r = __builtin_amdgcn_fractf(r);
  float s = __builtin_amdgcn_sinf(r);
  float u  = fmaf(s, 39.5f, 39.5f);          // (s+1)*0.5*79
  float fu = floorf(u);
  fu = fminf(fu, 78.0f);
  float w = u - fu;
  int addr = (pre.gb[jm] + (int)fu + ((J < 6) ? 0 : 960)) << 3;
  const uint2* pe = (const uint2*)(lds + addr);
  uint2 ua = pe[0];     // quant i0   (4 f16)
  uint2 ub = pe[1];     // quant i0+1 (4 f16)
  h2 a0 = bch2(ua.x), a1 = bch2(ua.y), b0 = bch2(ub.x), b1 = bch2(ub.y);
  h2 wh = cvtpk(w, w);
  h2 f01 = __builtin_elementwise_fma(b0 - a0, wh, a0);
  h2 f23 = __builtin_elementwise_fma(b1 - a1, wh, a1);
  w01 = bcu(f01);
  w23 = bcu(f23);
}

template<int T>
static __device__ __forceinline__ half8 enc2(const Pre& pre, float q0, float q1, float q2,
                                             const unsigned char* lds) {
  uint32_t a, b, c, d;
  gather<2 * T + 0>(pre, q0, q1, q2, lds, a, b);
  gather<2 * T + 1>(pre, q0, q1, q2, lds, c, d);
  return mk_frag(a, b, c, d);
}

__global__ __launch_bounds__(256, 3)
void qff_fwd(const float* __restrict__ pos, const float* __restrict__ dir,
             const float* __restrict__ grid,
             const float* __restrict__ w1, const float* __restrict__ w2,
             const float* __restrict__ wc1, const float* __restrict__ wc2,
             const float* __restrict__ wc3,
             float* __restrict__ out, int Npts) {
  __shared__ __align__(16) unsigned char smem[LDSZ];
  const int tid = threadIdx.x;

  // ---- stage weights (W^T, f16, frag-shaped) + grid (f16) into LDS ----
  for (int i = tid; i < WBYTES / 4; i += 256) ((uint32_t*)smem)[i] = 0;
  __syncthreads();
  for (int i = tid; i < 6144; i += 256)   // w1 [96][64]
    *(unsigned short*)(smem + W1OFF  + (i & 63) * 208 + (i >> 6) * 2) = f16b(w1[i]);
  for (int i = tid; i < 1024; i += 256)   // w2 [64][16]
    *(unsigned short*)(smem + W2OFF  + (i & 15) * 144 + (i >> 4) * 2) = f16b(w2[i]);
  for (int i = tid; i < 1984; i += 256)   // wc1 [31][64]
    *(unsigned short*)(smem + WC1OFF + (i & 63) * 80  + (i >> 6) * 2) = f16b(wc1[i]);
  for (int i = tid; i < 4096; i += 256)   // wc2 [64][64]
    *(unsigned short*)(smem + WC2OFF + (i & 63) * 144 + (i >> 6) * 2) = f16b(wc2[i]);
  for (int i = tid; i < 192; i += 256)    // wc3 [64][3]
    *(unsigned short*)(smem + WC3OFF + (i % 3) * 144 + (i / 3) * 2) = f16b(wc3[i]);
  for (int i = tid; i < 3840; i += 256) { // grid [24][80][4] f32 -> f16 pairs
    float2 v = ((const float2*)grid)[i];
    *(uint32_t*)(smem + GROFF + i * 4) = (((uint32_t)f16b(v.y)) << 16) | f16b(v.x);
  }
  __syncthreads();

  const int lane = tid & 63;
  const int wid  = tid >> 6;
  const int g    = lane >> 5;
  const int o    = lane & 31;

  // ---- per-lane constants ----
  constexpr float IV = 0.15915494309189535f;
  constexpr float F0 = 2.0f, F1 = 6.349604207872798f, F2 = 20.158736798317971f, F3 = 64.0f;
  const float M0c[6] = {F0*IV, F0*IV, F1*IV, F1*IV, F2*IV, F3*IV};
  const float M1c[6] = {F0*IV, F1*IV, F2*IV, F2*IV, F3*IV, F3*IV};
  const int   GB0[6] = {4608, 4688, 4928, 5008, 5248, 5328};
  const int   GB1[6] = {4768, 4848, 5088, 5168, 5408, 5488};
  Pre pre;
#pragma unroll
  for (int j = 0; j < 6; ++j) {
    pre.m[j]  = g ? M1c[j] : M0c[j];
    pre.gb[j] = g ? GB1[j] : GB0[j];
  }
  pre.a13 = o * 208 + g * 16;
  pre.a9  = o * 144 + g * 16;
  pre.a5  = o * 80  + g * 16;

  const f32x16 Z = {0,0,0,0, 0,0,0,0, 0,0,0,0, 0,0,0,0};
  const int ntile = Npts >> 7;   // 128 points per block-tile
  int tb = blockIdx.x;
  if (tb >= ntile) return;

  int p = (tb << 7) + (wid << 5) + o;
  float px = pos[3*p+0], py = pos[3*p+1], pz = pos[3*p+2];
  float dx = dir[3*p+0], dy = dir[3*p+1], dz = dir[3*p+2];

  for (; tb < ntile; tb += gridDim.x) {
    // prefetch next tile's point data (lands during the MLP below)
    int tbn = tb + gridDim.x;
    int pn  = ((tbn < ntile ? tbn : ntile - 1) << 7) + (wid << 5) + o;
    float npx = pos[3*pn+0], npy = pos[3*pn+1], npz = pos[3*pn+2];
    float ndx = dir[3*pn+0], ndy = dir[3*pn+1], ndz = dir[3*pn+2];

    // q-rotation: makes the dim pattern identical for both lane halves
    float q0 = g ? pz : px;
    float q1 = g ? px : py;
    float q2 = g ? py : pz;

    // ---- L1: enc(96) @ w_geom1 -> h1(64) ----
    f32x16 acc0 = Z, acc1 = Z;
#define L1STEP(T) { half8 bf = enc2<T>(pre, q0, q1, q2, smem); \
                    acc0 = MFMA(ldw(smem, pre.a13, W1OFF + T*32), bf, acc0); \
                    acc1 = MFMA(ldw(smem, pre.a13, W1OFF + 6656 + T*32), bf, acc1); }
    L1STEP(0) L1STEP(1) L1STEP(2) L1STEP(3) L1STEP(4) L1STEP(5)
#undef L1STEP

    half8 hb0 = packB<0, true>(acc0), hb1 = packB<8, true>(acc0);
    half8 hb2 = packB<0, true>(acc1), hb3 = packB<8, true>(acc1);

    // ---- L2: h1 @ w_geom2 -> f(16), no relu ----
    f32x16 acc2 = Z;
    acc2 = MFMA(ldw(smem, pre.a9, W2OFF +  0), hb0, acc2);
    acc2 = MFMA(ldw(smem, pre.a9, W2OFF + 32), hb1, acc2);
    acc2 = MFMA(ldw(smem, pre.a9, W2OFF + 64), hb2, acc2);
    acc2 = MFMA(ldw(smem, pre.a9, W2OFF + 96), hb3, acc2);
    float sigma = __expf(acc2[0] - 1.0f);   // g==0 lanes: reg0 = out0 = raw_sigma

    // ---- spherical harmonics: lane half g supplies sh[8g..8g+7] ----
    float xx = dx*dx, yy = dy*dy, zz = dz*dz;
    float xy = dx*dy, yz = dy*dz, xz = dx*dz;
    float s0, s1, s2, s3, s4, s5, s6, s7;
    if (g == 0) {
      s0 = 0.28209479177387814f;
      s1 = -0.48860251190291987f * dy;
      s2 =  0.48860251190291987f * dz;
      s3 = -0.48860251190291987f * dx;
      s4 =  1.0925484305920792f * xy;
      s5 = -1.0925484305920792f * yz;
      s6 =  0.94617469575756f * zz - 0.31539156525252f;
      s7 = -1.0925484305920792f * xz;
    } else {
      s0 =  0.5462742152960396f * (xx - yy);
      s1 = -0.5900435899266435f * dy * (3.0f * xx - yy);
      s2 =  2.890611442640554f * xy * dz;
      s3 = -0.4570457994644657f * dy * (4.0f * zz - xx - yy);
      s4 =  0.37317633259011546f * dz * (2.0f * zz - 3.0f * xx - 3.0f * yy);
      s5 = -0.4570457994644657f * dx * (4.0f * zz - xx - yy);
      s6 =  1.445305721320277f * dz * (xx - yy);
      s7 = -0.5900435899266435f * dx * (xx - 3.0f * yy);
    }
    half8 shB = mk_frag(pkrtz(s0, s1), pkrtz(s2, s3), pkrtz(s4, s5), pkrtz(s6, s7));

    // ---- feature = f[1..15] -> hc k 16..30 (k=31 hits zeroed wc1 row) ----
    uint32_t e0 = pkrtz(acc2[1], acc2[2]);
    uint32_t e2 = pkrtz(acc2[5], acc2[6]);
    plswap_u(e0, e2);
    float a3 = acc2[3], b7 = acc2[7];
    plswap_f(a3, b7);
    float cc0 = acc2[0], d4 = acc2[4];
    plswap_f(cc0, d4);
    uint32_t e1 = pkrtz(a3, d4);
    uint32_t e3 = pkrtz(b7, acc2[4]);
    half8 featB = mk_frag(e0, e1, e2, e3);

    // ---- L3: hc(32) @ w_color1 -> h2(64), relu ----
    f32x16 acc3a = Z, acc3b = Z;
    acc3a = MFMA(ldw(smem, pre.a5, WC1OFF +  0), shB,   acc3a);
    acc3a = MFMA(ldw(smem, pre.a5, WC1OFF + 32), featB, acc3a);
    acc3b = MFMA(ldw(smem, pre.a5, WC1OFF + 2560 +  0), shB,   acc3b);
    acc3b = MFMA(ldw(smem, pre.a5, WC1OFF + 2560 + 32), featB, acc3b);

    half8 g2b0 = packB<0, true>(acc3a), g2b1 = packB<8, true>(acc3a);
    half8 g2b2 = packB<0, true>(acc3b), g2b3 = packB<8, true>(acc3b);

    // ---- L4: h2 @ w_color2 -> h3(64), relu ----
    f32x16 acc4a = Z, acc4b = Z;
    acc4a = MFMA(ldw(smem, pre.a9, WC2OFF +  0), g2b0, acc4a);
    acc4a = MFMA(ldw(smem, pre.a9, WC2OFF + 32), g2b1, acc4a);
    acc4a = MFMA(ldw(smem, pre.a9, WC2OFF + 64), g2b2, acc4a);
    acc4a = MFMA(ldw(smem, pre.a9, WC2OFF + 96), g2b3, acc4a);
    acc4b = MFMA(ldw(smem, pre.a9, WC2OFF + 4608 +  0), g2b0, acc4b);
    acc4b = MFMA(ldw(smem, pre.a9, WC2OFF + 4608 + 32), g2b1, acc4b);
    acc4b = MFMA(ldw(smem, pre.a9, WC2OFF + 4608 + 64), g2b2, acc4b);
    acc4b = MFMA(ldw(smem, pre.a9, WC2OFF + 4608 + 96), g2b3, acc4b);

    half8 g3b0 = packB<0, true>(acc4a), g3b1 = packB<8, true>(acc4a);
    half8 g3b2 = packB<0, true>(acc4b), g3b3 = packB<8, true>(acc4b);

    // ---- L5: h3 @ w_color3 -> rgb(3), sigmoid ----
    f32x16 acc5 = Z;
    acc5 = MFMA(ldw(smem, pre.a9, WC3OFF +  0), g3b0, acc5);
    acc5 = MFMA(ldw(smem, pre.a9, WC3OFF + 32), g3b1, acc5);
    acc5 = MFMA(ldw(smem, pre.a9, WC3OFF + 64), g3b2, acc5);
    acc5 = MFMA(ldw(smem, pre.a9, WC3OFF + 96), g3b3, acc5);

    if (lane < 32) {   // g==0 lanes hold outs 0..3 in regs 0..3
      float rr = __builtin_amdgcn_rcpf(1.0f + __expf(-acc5[0]));
      float gg = __builtin_amdgcn_rcpf(1.0f + __expf(-acc5[1]));
      float bb = __builtin_amdgcn_rcpf(1.0f + __expf(-acc5[2]));
      out[3 * p + 0] = rr;
      out[3 * p + 1] = gg;
      out[3 * p + 2] = bb;
      out[3 * Npts + p] = sigma;
    }

    p = pn;
    px = npx; py = npy; pz = npz;
    dx = ndx; dy = ndy; dz = ndz;
  }
}

extern "C" void kernel_launch(void* const* d_in, const int* in_sizes, int n_in,
                              void* d_out, int out_size, void* d_ws, size_t ws_size,
                              hipStream_t stream) {
  const float* pos  = (const float*)d_in[0];
  const float* dirs = (const float*)d_in[1];
  const float* grid = (const float*)d_in[2];
  const float* w1   = (const float*)d_in[3];
  const float* w2   = (const float*)d_in[4];
  const float* wc1  = (const float*)d_in[5];
  const float* wc2  = (const float*)d_in[6];
  const float* wc3  = (const float*)d_in[7];
  float* out = (float*)d_out;
  const int Npts = in_sizes[0] / 3;

  qff_fwd<<<dim3(768), dim3(256), 0, stream>>>(pos, dirs, grid, w1, w2, wc1, wc2, wc3,
                                               out, Npts);
}